// Round 5
// baseline (124.799 us; speedup 1.0000x reference)
//
#include <hip/hip_runtime.h>
#include <math.h>

#define NB 8192
#define DK 256
#define BM 128
#define NTILE 64                    // NB/BM
#define NBLK (NTILE*(NTILE+1)/2)    // 2080 upper-triangular tiles
#define GRID 512                    // 2 blocks/CU; each owns 4-5 tiles

typedef __bf16 bf16x8 __attribute__((ext_vector_type(8)));
typedef float f32x4 __attribute__((ext_vector_type(4)));

__device__ inline unsigned short f2bf(float f) {
  unsigned u = __float_as_uint(f);
  u += 0x7fffu + ((u >> 16) & 1u);          // round-to-nearest-even
  return (unsigned short)(u >> 16);
}

// ---------------- Kernel 1: L2-normalize rows, fp32 -> bf16
__global__ __launch_bounds__(256) void normalize_kernel(
    const float* __restrict__ emb, unsigned short* __restrict__ ebf) {
  int wave = threadIdx.x >> 6;
  int lane = threadIdx.x & 63;
  int row = blockIdx.x * 4 + wave;                  // one wave per row
  const float4* src = reinterpret_cast<const float4*>(emb + (size_t)row * DK) + lane;
  float4 v = *src;
  float ss = v.x * v.x + v.y * v.y + v.z * v.z + v.w * v.w;
  #pragma unroll
  for (int m = 1; m < 64; m <<= 1) ss += __shfl_xor(ss, m, 64);
  float inv = 1.0f / sqrtf(ss);
  ushort4 o;
  o.x = f2bf(v.x * inv);
  o.y = f2bf(v.y * inv);
  o.z = f2bf(v.z * inv);
  o.w = f2bf(v.w * inv);
  *reinterpret_cast<ushort4*>(ebf + (size_t)row * DK + lane * 4) = o;
}

// ---------------- Kernel 2: barrier-free direct-from-L2 GEMM + fused epilogue.
// A-panel in registers (reused across a row of tiles); B-fragments read
// straight from global (ebf is 4 MB, fully L2-resident). No LDS staging,
// no __syncthreads in the loop -> waves drift and self-pipeline.
__global__ __launch_bounds__(256, 2) void circle_gemm(
    const unsigned short* __restrict__ ebf, const int* __restrict__ labels,
    float* __restrict__ partial) {
  __shared__ float wsum[4];

  int b = blockIdx.x;
  int bid = (b & 7) * (GRID / 8) + (b >> 3);        // XCD swizzle (512 = 8*64)
  int start = (bid * NBLK) / GRID;
  int end = ((bid + 1) * NBLK) / GRID;

  int tid = threadIdx.x;
  int lane = tid & 63;
  int wave = tid >> 6;
  int wr = (wave >> 1) * 64;                        // wave's 64x64 sub-tile
  int wc = (wave & 1) * 64;
  int frow = lane & 15;
  int khi8 = (lane >> 4) * 8;                       // k-subgroup (elements)

  // decode flat triangular index -> (tr, tc)
  int rem = start, tr = 0;
  while (rem >= NTILE - tr) { rem -= NTILE - tr; ++tr; }
  int tc = tr + rem;

  bf16x8 a[4][8];                                   // A-panel frags: 128 VGPR
  int labR[16];

  auto loadA = [&](int trr) {
    int row0 = trr * BM;
    #pragma unroll
    for (int m = 0; m < 4; ++m) {
      const unsigned short* arow =
          ebf + (size_t)(row0 + wr + m * 16 + frow) * DK + khi8;
      #pragma unroll
      for (int s = 0; s < 8; ++s)
        a[m][s] = *reinterpret_cast<const bf16x8*>(arow + s * 32);
    }
    int rbase = row0 + wr + ((lane >> 4) << 2);
    #pragma unroll
    for (int m = 0; m < 4; ++m)
      #pragma unroll
      for (int e = 0; e < 4; ++e)
        labR[m * 4 + e] = labels[rbase + m * 16 + e];
  };

  loadA(tr);
  float lsum = 0.0f;

  for (int t = start; t < end; ++t) {
    int col0 = tc * BM;
    const unsigned short* bbase = ebf + (size_t)(col0 + wc + frow) * DK + khi8;
    int labC[4];
    #pragma unroll
    for (int n = 0; n < 4; ++n) labC[n] = labels[col0 + wc + frow + n * 16];

    f32x4 accf[4][4] = {};
    #pragma unroll
    for (int s = 0; s < 8; ++s) {
      bf16x8 bfr[4];                                // B frags direct from L2
      #pragma unroll
      for (int n = 0; n < 4; ++n)
        bfr[n] = *reinterpret_cast<const bf16x8*>(bbase + (size_t)n * 16 * DK + s * 32);
      #pragma unroll
      for (int m = 0; m < 4; ++m)
        #pragma unroll
        for (int n = 0; n < 4; ++n)
          accf[m][n] = __builtin_amdgcn_mfma_f32_16x16x32_bf16(
              a[m][s], bfr[n], accf[m][n], 0, 0, 0);
    }

    // epilogue: circle-loss terms; C/D layout col=lane&15, row=(lane>>4)*4+reg
    float tsum = 0.0f;
    #pragma unroll
    for (int m = 0; m < 4; ++m) {
      #pragma unroll
      for (int n = 0; n < 4; ++n) {
        #pragma unroll
        for (int e = 0; e < 4; ++e) {
          float sv = accf[m][n][e];
          bool pos = (labR[m * 4 + e] == labC[n]);
          float relu = pos ? fmaxf(sv - 0.75f, 0.0f) : fmaxf(0.25f - sv, 0.0f);
          float arg  = pos ? (2.5f - 2.0f * sv)      : (2.0f * sv + 0.5f);
          tsum += relu * __expf(arg);
        }
      }
    }
    lsum += (tc != tr) ? 2.0f * tsum : tsum;        // symmetry doubling

    int ntr = tr, ntc = tc + 1;                     // next triangular tile
    if (ntc == NTILE) { ++ntr; ntc = ntr; }
    if (t + 1 < end && ntr != tr) loadA(ntr);       // rare: row change
    tr = ntr; tc = ntc;
  }

  #pragma unroll
  for (int m = 32; m; m >>= 1) lsum += __shfl_xor(lsum, m, 64);
  if (lane == 0) wsum[wave] = lsum;
  __syncthreads();
  if (tid == 0) partial[bid] = wsum[0] + wsum[1] + wsum[2] + wsum[3];
}

// ---------------- Kernel 3: reduce partials + log1p (one block)
__global__ __launch_bounds__(256) void finalize_kernel(
    const float* __restrict__ partial, float* __restrict__ out) {
  __shared__ float wsum[4];
  int tid = threadIdx.x;
  float s = partial[tid] + partial[tid + 256];      // GRID = 512
  #pragma unroll
  for (int m = 32; m; m >>= 1) s += __shfl_xor(s, m, 64);
  if ((tid & 63) == 0) wsum[tid >> 6] = s;
  __syncthreads();
  if (tid == 0) out[0] = logf(1.0f + wsum[0] + wsum[1] + wsum[2] + wsum[3]);
}

extern "C" void kernel_launch(void* const* d_in, const int* in_sizes, int n_in,
                              void* d_out, int out_size, void* d_ws, size_t ws_size,
                              hipStream_t stream) {
  const float* emb = (const float*)d_in[0];
  const int* labels = (const int*)d_in[1];
  float* out = (float*)d_out;
  unsigned short* ebf = (unsigned short*)d_ws;                       // 4 MB bf16 E
  float* partial = (float*)((char*)d_ws + (size_t)NB * DK * 2);      // GRID floats

  hipLaunchKernelGGL(normalize_kernel, dim3(NB / 4), dim3(256), 0, stream, emb, ebf);
  hipLaunchKernelGGL(circle_gemm, dim3(GRID), dim3(256), 0, stream, ebf, labels, partial);
  hipLaunchKernelGGL(finalize_kernel, dim3(1), dim3(256), 0, stream, partial, out);
}